// Round 18
// baseline (31.994 us; speedup 1.0000x reference)
//
#include <hip/hip_runtime.h>
#include <hip/hip_bf16.h>

typedef __attribute__((ext_vector_type(8))) short bf16x8;
typedef __attribute__((ext_vector_type(4))) float f32x4;

#define NB 1024
#define ND 256
#define MARGINF 0.3f
#define BIGV 1e9f
#define D2R 0.017453292519943295f
#define HD2R 0.008726646259971648f

// haversine 'a' thresholds: sin^2(T/(2*6371000)) (validated rounds 1-17)
#define A_POS 3.8495040e-12f   // 25 m
#define A_NEG 6.1592064e-11f   // 100 m

__device__ __forceinline__ float d4(float4 a, float4 b, float acc) {
    return fmaf(a.x,b.x, fmaf(a.y,b.y, fmaf(a.z,b.z, fmaf(a.w,b.w, acc))));
}

__device__ __forceinline__ void splitHL(float4 v0, float4 v1, bf16x8& H, bf16x8& L) {
    float f[8] = {v0.x, v0.y, v0.z, v0.w, v1.x, v1.y, v1.z, v1.w};
    #pragma unroll
    for (int q = 0; q < 8; ++q) {
        __hip_bfloat16 h = __float2bfloat16(f[q]);
        float hf = __bfloat162float(h);
        __hip_bfloat16 l = __float2bfloat16(f[q] - hf);
        H[q] = *(short*)&h;
        L[q] = *(short*)&l;
    }
}

// K1: r11-exact MFMA gram (best measured config). 64x64 tile, 256 thr, 2x2
// waves, acc[2][2]; in-register H/L split fills the MFMA shadow.
// G = HH' + LH' + HL'; d^2 = sq_i + sq_j - 2G (exact fp32 norms).
// Block 0 zeroes the K2 reduction cells (read only after this kernel -> safe).
__global__ __launch_bounds__(256) void gram_mfma(
    const float* __restrict__ emb, const float* __restrict__ gps,
    float* __restrict__ sEnc, float* __restrict__ pP, float* __restrict__ flags)
{
    __shared__ float  sSqI[64], sSqJ[64];
    __shared__ float4 sGI[64], sGJ[64];
    __shared__ float  sRed[64][33];

    const int tid = threadIdx.x, lane = tid & 63, w = tid >> 6;
    const int wr = w >> 1, wc = w & 1;
    const int ib = blockIdx.x & 15, jb = blockIdx.x >> 4;
    const int i0 = ib*64, j0 = jb*64;
    const int lr = lane & 15, lk = lane >> 4;
    const float4* __restrict__ emb4 = (const float4*)emb;

    if (blockIdx.x == 0 && tid < 3) flags[tid] = 0.f;   // packed-double(2) + counter

    // prologue: row norms (exact fp32) + gps scalars
    {
        const int half = tid & 1, r = (tid >> 1) & 63;
        const int base = (tid < 128) ? i0 : j0;
        const float4* rp = emb4 + (size_t)(base + r)*64 + half*32;
        float s = 0.f;
        #pragma unroll
        for (int q = 0; q < 32; ++q) s = d4(rp[q], rp[q], s);
        s += __shfl_xor(s, 1);
        if (half == 0) { if (tid < 128) sSqI[r] = s; else sSqJ[r] = s; }
    }
    if (tid < 128) {
        const int r = tid & 63;
        const int base = (tid < 64) ? i0 : j0;
        float2 g = ((const float2*)gps)[base + r];
        float4 gi = make_float4(g.x, g.y, cosf(g.x * D2R), 0.f);
        if (tid < 64) sGI[r] = gi; else sGJ[r] = gi;
    }
    __syncthreads();

    // MFMA loop: 8 k-windows x {8 loads -> 4 splits -> 12 MFMAs}
    f32x4 acc[2][2] = {};
    #pragma unroll 2
    for (int k8 = 0; k8 < 8; ++k8) {
        const int co = k8*8 + lk*2;
        const float4* pa0 = emb4 + (size_t)(i0 + wr*32      + lr)*64 + co;
        const float4* pa1 = emb4 + (size_t)(i0 + wr*32 + 16 + lr)*64 + co;
        const float4* pb0 = emb4 + (size_t)(j0 + wc*32      + lr)*64 + co;
        const float4* pb1 = emb4 + (size_t)(j0 + wc*32 + 16 + lr)*64 + co;
        bf16x8 a0H,a0L,a1H,a1L,b0H,b0L,b1H,b1L;
        splitHL(pa0[0], pa0[1], a0H, a0L);
        splitHL(pa1[0], pa1[1], a1H, a1L);
        splitHL(pb0[0], pb0[1], b0H, b0L);
        splitHL(pb1[0], pb1[1], b1H, b1L);
        acc[0][0] = __builtin_amdgcn_mfma_f32_16x16x32_bf16(a0H, b0H, acc[0][0], 0,0,0);
        acc[0][1] = __builtin_amdgcn_mfma_f32_16x16x32_bf16(a0H, b1H, acc[0][1], 0,0,0);
        acc[1][0] = __builtin_amdgcn_mfma_f32_16x16x32_bf16(a1H, b0H, acc[1][0], 0,0,0);
        acc[1][1] = __builtin_amdgcn_mfma_f32_16x16x32_bf16(a1H, b1H, acc[1][1], 0,0,0);
        acc[0][0] = __builtin_amdgcn_mfma_f32_16x16x32_bf16(a0L, b0H, acc[0][0], 0,0,0);
        acc[0][1] = __builtin_amdgcn_mfma_f32_16x16x32_bf16(a0L, b1H, acc[0][1], 0,0,0);
        acc[1][0] = __builtin_amdgcn_mfma_f32_16x16x32_bf16(a1L, b0H, acc[1][0], 0,0,0);
        acc[1][1] = __builtin_amdgcn_mfma_f32_16x16x32_bf16(a1L, b1H, acc[1][1], 0,0,0);
        acc[0][0] = __builtin_amdgcn_mfma_f32_16x16x32_bf16(a0H, b0L, acc[0][0], 0,0,0);
        acc[0][1] = __builtin_amdgcn_mfma_f32_16x16x32_bf16(a0H, b1L, acc[0][1], 0,0,0);
        acc[1][0] = __builtin_amdgcn_mfma_f32_16x16x32_bf16(a1H, b0L, acc[1][0], 0,0,0);
        acc[1][1] = __builtin_amdgcn_mfma_f32_16x16x32_bf16(a1H, b1L, acc[1][1], 0,0,0);
    }

    // epilogue: d^2, masks, sEnc encode, per-row pmax partials
    float sqj[2]; float4 gj2[2];
    sqj[0] = sSqJ[wc*32 + lr];      gj2[0] = sGJ[wc*32 + lr];
    sqj[1] = sSqJ[wc*32 + 16 + lr]; gj2[1] = sGJ[wc*32 + 16 + lr];

    #pragma unroll
    for (int fi = 0; fi < 2; ++fi) {
        #pragma unroll
        for (int r = 0; r < 4; ++r) {
            const int rl = wr*32 + fi*16 + lk*4 + r;
            const int gi = i0 + rl;
            const float sqi = sSqI[rl];
            const float4 gvi = sGI[rl];
            float pmax = -1.f;
            #pragma unroll
            for (int fj = 0; fj < 2; ++fj) {
                const int gj = j0 + wc*32 + fj*16 + lr;
                float d2v = sqi + sqj[fj] - 2.f*acc[fi][fj][r];
                d2v = d2v > 0.f ? d2v : 0.f;
                const float sla = sinf((gj2[fj].x - gvi.x) * HD2R);
                const float slo = sinf((gj2[fj].y - gvi.y) * HD2R);
                const float hav = fmaf(sla, sla, (gvi.z * gj2[fj].z) * (slo*slo));
                const bool pos = (hav < A_POS) && (gi != gj);
                const bool neg = (hav > A_NEG);
                pmax = fmaxf(pmax, pos ? d2v : -1.f);
                sEnc[(size_t)gi*NB + gj] = neg ? d2v : BIGV;
            }
            sRed[rl][lr + 16*wc] = pmax;
        }
    }
    __syncthreads();
    if (tid < 64) {
        float m = sRed[tid][0];
        #pragma unroll
        for (int c = 1; c < 32; ++c) m = fmaxf(m, sRed[tid][c]);
        pP[(i0 + tid)*16 + jb] = m;
    }
}

// K2: per-row finalize + FENCE-FREE packed-double atomic tail.
// Each block: one atomicAdd(double) of (st + sv*65536), explicit vmcnt(0)
// (completion at coherence point, no cache flush), then the done-counter.
// The 256th incrementer reads the cell atomically and emits the loss.
__global__ __launch_bounds__(256) void rows_final(
    const float* __restrict__ sEnc, const float* __restrict__ pP,
    float* __restrict__ flags, float* __restrict__ out)
{
    __shared__ float sT[4], sV[4];
    const int tid = threadIdx.x, lane = tid & 63, w = tid >> 6;
    const int i = blockIdx.x*4 + w;

    float p = pP[i*16 + (lane & 15)];
    #pragma unroll
    for (int off = 1; off < 16; off <<= 1) p = fmaxf(p, __shfl_xor(p, off));
    const float dap2 = p;
    const bool has_pos = dap2 > -0.5f;
    float lo2 = -1.f, hi2 = -1.f;
    if (has_pos) { const float hb = sqrtf(dap2) + MARGINF; lo2 = dap2; hi2 = hb*hb; }

    float nmin = BIGV, smin = BIGV;
    const float4* __restrict__ row = (const float4*)sEnc + (size_t)i*256;
    #pragma unroll
    for (int pss = 0; pss < 4; ++pss) {
        const float4 x = row[pss*64 + lane];
        #pragma unroll
        for (int q = 0; q < 4; ++q) {
            const float xc = (q==0) ? x.x : (q==1) ? x.y : (q==2) ? x.z : x.w;
            nmin = fminf(nmin, xc);
            smin = fminf(smin, (xc > lo2 && xc < hi2) ? xc : BIGV);
        }
    }
    #pragma unroll
    for (int off = 1; off < 64; off <<= 1) {
        nmin = fminf(nmin, __shfl_xor(nmin, off));
        smin = fminf(smin, __shfl_xor(smin, off));
    }
    if (lane == 0) {
        const bool has_neg  = nmin < 0.5f*BIGV;
        const bool has_semi = smin < 0.5f*BIGV;
        const float dan2 = has_semi ? smin : nmin;
        const float dap  = has_pos ? sqrtf(dap2) : 0.f;
        float t = dap - sqrtf(dan2) + MARGINF;
        t = t > 0.f ? t : 0.f;
        const bool valid = has_pos && has_neg;
        sT[w] = valid ? t : 0.f;
        sV[w] = valid ? 1.f : 0.f;
    }
    __syncthreads();
    if (tid == 0) {
        const float st = sT[0]+sT[1]+sT[2]+sT[3];
        const float sv = sV[0]+sV[1]+sV[2]+sV[3];
        double* dsum = (double*)flags;             // 8B-aligned (checked host-side)
        unsigned* dcnt = (unsigned*)(flags + 2);
        const double my = (double)st + (double)sv * 65536.0;
        atomicAdd(dsum, my);
        asm volatile("s_waitcnt vmcnt(0)" ::: "memory");   // packed-add complete
        const unsigned oc = atomicAdd(dcnt, 1u);
        if (oc == 255u) {                          // last block, order-independent
            const double fin = atomicAdd(dsum, 0.0);
            const double svt = floor(fin / 65536.0);
            const double stt = fin - svt * 65536.0;
            out[0] = (float)(stt / (svt > 1.0 ? svt : 1.0));
        }
    }
}

extern "C" void kernel_launch(void* const* d_in, const int* in_sizes, int n_in,
                              void* d_out, int out_size, void* d_ws, size_t ws_size,
                              hipStream_t stream) {
    const float* emb = (const float*)d_in[0];   // [1024,256] f32
    const float* gps = (const float*)d_in[1];   // [1024,2]  f32
    float* ws = (float*)d_ws;

    float* sEnc  = ws;                    // 1024*1024 f32 = 4 MB
    float* pP    = ws + 1048576;          // 1024*16
    float* flags = pP + 16384;            // double cell (8B-aligned) + counter

    gram_mfma<<<256, 256, 0, stream>>>(emb, gps, sEnc, pP, flags);
    rows_final<<<256, 256, 0, stream>>>(sEnc, pP, flags, (float*)d_out);
}

// Round 19
// 31.731 us; speedup vs baseline: 1.0083x; 1.0083x over previous
//
#include <hip/hip_runtime.h>
#include <hip/hip_bf16.h>

typedef __attribute__((ext_vector_type(8))) short bf16x8;
typedef __attribute__((ext_vector_type(4))) float f32x4;

#define NB 1024
#define ND 256
#define MARGINF 0.3f
#define BIGV 1e9f
#define D2R 0.017453292519943295f
#define HD2R 0.008726646259971648f

// haversine 'a' thresholds: sin^2(T/(2*6371000)) (validated rounds 1-18)
#define A_POS 3.8495040e-12f   // 25 m
#define A_NEG 6.1592064e-11f   // 100 m

__device__ __forceinline__ float d4(float4 a, float4 b, float acc) {
    return fmaf(a.x,b.x, fmaf(a.y,b.y, fmaf(a.z,b.z, fmaf(a.w,b.w, acc))));
}

__device__ __forceinline__ void splitHL(float4 v0, float4 v1, bf16x8& H, bf16x8& L) {
    float f[8] = {v0.x, v0.y, v0.z, v0.w, v1.x, v1.y, v1.z, v1.w};
    #pragma unroll
    for (int q = 0; q < 8; ++q) {
        __hip_bfloat16 h = __float2bfloat16(f[q]);
        float hf = __bfloat162float(h);
        __hip_bfloat16 l = __float2bfloat16(f[q] - hf);
        H[q] = *(short*)&h;
        L[q] = *(short*)&l;
    }
}

// K1: r11-exact MFMA gram (best measured config, 27.4 us total in 3-node form).
// 64x64 tile, 256 thr, 2x2 waves, acc[2][2]; in-register H/L split fills the
// MFMA shadow. G = HH' + LH' + HL'; d^2 = sq_i + sq_j - 2G (exact fp32 norms).
// Block 0 zeroes K2's reduction cells (K2 reads them only after K1 -> safe).
__global__ __launch_bounds__(256) void gram_mfma(
    const float* __restrict__ emb, const float* __restrict__ gps,
    float* __restrict__ sEnc, float* __restrict__ pP, float* __restrict__ flags)
{
    __shared__ float  sSqI[64], sSqJ[64];
    __shared__ float4 sGI[64], sGJ[64];
    __shared__ float  sRed[64][33];

    const int tid = threadIdx.x, lane = tid & 63, w = tid >> 6;
    const int wr = w >> 1, wc = w & 1;
    const int ib = blockIdx.x & 15, jb = blockIdx.x >> 4;
    const int i0 = ib*64, j0 = jb*64;
    const int lr = lane & 15, lk = lane >> 4;
    const float4* __restrict__ emb4 = (const float4*)emb;

    if (blockIdx.x == 0 && tid < 4) flags[tid] = 0.f;   // double cell + counter

    // prologue: row norms (exact fp32) + gps scalars
    {
        const int half = tid & 1, r = (tid >> 1) & 63;
        const int base = (tid < 128) ? i0 : j0;
        const float4* rp = emb4 + (size_t)(base + r)*64 + half*32;
        float s = 0.f;
        #pragma unroll
        for (int q = 0; q < 32; ++q) s = d4(rp[q], rp[q], s);
        s += __shfl_xor(s, 1);
        if (half == 0) { if (tid < 128) sSqI[r] = s; else sSqJ[r] = s; }
    }
    if (tid < 128) {
        const int r = tid & 63;
        const int base = (tid < 64) ? i0 : j0;
        float2 g = ((const float2*)gps)[base + r];
        float4 gi = make_float4(g.x, g.y, cosf(g.x * D2R), 0.f);
        if (tid < 64) sGI[r] = gi; else sGJ[r] = gi;
    }
    __syncthreads();

    // MFMA loop: 8 k-windows x {8 loads -> 4 splits -> 12 MFMAs}
    f32x4 acc[2][2] = {};
    #pragma unroll 2
    for (int k8 = 0; k8 < 8; ++k8) {
        const int co = k8*8 + lk*2;
        const float4* pa0 = emb4 + (size_t)(i0 + wr*32      + lr)*64 + co;
        const float4* pa1 = emb4 + (size_t)(i0 + wr*32 + 16 + lr)*64 + co;
        const float4* pb0 = emb4 + (size_t)(j0 + wc*32      + lr)*64 + co;
        const float4* pb1 = emb4 + (size_t)(j0 + wc*32 + 16 + lr)*64 + co;
        bf16x8 a0H,a0L,a1H,a1L,b0H,b0L,b1H,b1L;
        splitHL(pa0[0], pa0[1], a0H, a0L);
        splitHL(pa1[0], pa1[1], a1H, a1L);
        splitHL(pb0[0], pb0[1], b0H, b0L);
        splitHL(pb1[0], pb1[1], b1H, b1L);
        acc[0][0] = __builtin_amdgcn_mfma_f32_16x16x32_bf16(a0H, b0H, acc[0][0], 0,0,0);
        acc[0][1] = __builtin_amdgcn_mfma_f32_16x16x32_bf16(a0H, b1H, acc[0][1], 0,0,0);
        acc[1][0] = __builtin_amdgcn_mfma_f32_16x16x32_bf16(a1H, b0H, acc[1][0], 0,0,0);
        acc[1][1] = __builtin_amdgcn_mfma_f32_16x16x32_bf16(a1H, b1H, acc[1][1], 0,0,0);
        acc[0][0] = __builtin_amdgcn_mfma_f32_16x16x32_bf16(a0L, b0H, acc[0][0], 0,0,0);
        acc[0][1] = __builtin_amdgcn_mfma_f32_16x16x32_bf16(a0L, b1H, acc[0][1], 0,0,0);
        acc[1][0] = __builtin_amdgcn_mfma_f32_16x16x32_bf16(a1L, b0H, acc[1][0], 0,0,0);
        acc[1][1] = __builtin_amdgcn_mfma_f32_16x16x32_bf16(a1L, b1H, acc[1][1], 0,0,0);
        acc[0][0] = __builtin_amdgcn_mfma_f32_16x16x32_bf16(a0H, b0L, acc[0][0], 0,0,0);
        acc[0][1] = __builtin_amdgcn_mfma_f32_16x16x32_bf16(a0H, b1L, acc[0][1], 0,0,0);
        acc[1][0] = __builtin_amdgcn_mfma_f32_16x16x32_bf16(a1H, b0L, acc[1][0], 0,0,0);
        acc[1][1] = __builtin_amdgcn_mfma_f32_16x16x32_bf16(a1H, b1L, acc[1][1], 0,0,0);
    }

    // epilogue: d^2, masks, sEnc encode, per-row pmax partials
    float sqj[2]; float4 gj2[2];
    sqj[0] = sSqJ[wc*32 + lr];      gj2[0] = sGJ[wc*32 + lr];
    sqj[1] = sSqJ[wc*32 + 16 + lr]; gj2[1] = sGJ[wc*32 + 16 + lr];

    #pragma unroll
    for (int fi = 0; fi < 2; ++fi) {
        #pragma unroll
        for (int r = 0; r < 4; ++r) {
            const int rl = wr*32 + fi*16 + lk*4 + r;
            const int gi = i0 + rl;
            const float sqi = sSqI[rl];
            const float4 gvi = sGI[rl];
            float pmax = -1.f;
            #pragma unroll
            for (int fj = 0; fj < 2; ++fj) {
                const int gj = j0 + wc*32 + fj*16 + lr;
                float d2v = sqi + sqj[fj] - 2.f*acc[fi][fj][r];
                d2v = d2v > 0.f ? d2v : 0.f;
                const float sla = sinf((gj2[fj].x - gvi.x) * HD2R);
                const float slo = sinf((gj2[fj].y - gvi.y) * HD2R);
                const float hav = fmaf(sla, sla, (gvi.z * gj2[fj].z) * (slo*slo));
                const bool pos = (hav < A_POS) && (gi != gj);
                const bool neg = (hav > A_NEG);
                pmax = fmaxf(pmax, pos ? d2v : -1.f);
                sEnc[(size_t)gi*NB + gj] = neg ? d2v : BIGV;
            }
            sRed[rl][lr + 16*wc] = pmax;
        }
    }
    __syncthreads();
    if (tid < 64) {
        float m = sRed[tid][0];
        #pragma unroll
        for (int c = 1; c < 32; ++c) m = fmaxf(m, sRed[tid][c]);
        pP[(i0 + tid)*16 + jb] = m;
    }
}

// K2: rows + loss in ONE kernel, LOW-CONTENTION tail: 16 blocks x 512 thr
// (8 waves -> 2/SIMD), each block scans 64 rows; tail = 16 packed-double
// atomics (not 256) + 16-count done counter; last block emits the loss.
__global__ __launch_bounds__(512) void rows_final(
    const float* __restrict__ sEnc, const float* __restrict__ pP,
    float* __restrict__ flags, float* __restrict__ out)
{
    __shared__ float sT[8], sV[8];
    const int tid = threadIdx.x, lane = tid & 63, w = tid >> 6;

    float accT = 0.f, accV = 0.f;
    #pragma unroll 2
    for (int p = 0; p < 8; ++p) {
        const int i = blockIdx.x*64 + w*8 + p;

        float pv = pP[i*16 + (lane & 15)];
        #pragma unroll
        for (int off = 1; off < 16; off <<= 1) pv = fmaxf(pv, __shfl_xor(pv, off));
        const float dap2 = pv;
        const bool has_pos = dap2 > -0.5f;
        float lo2 = -1.f, hi2 = -1.f;
        if (has_pos) { const float hb = sqrtf(dap2) + MARGINF; lo2 = dap2; hi2 = hb*hb; }

        float nmin = BIGV, smin = BIGV;
        const float4* __restrict__ row = (const float4*)sEnc + (size_t)i*256;
        #pragma unroll
        for (int pss = 0; pss < 4; ++pss) {
            const float4 x = row[pss*64 + lane];
            #pragma unroll
            for (int q = 0; q < 4; ++q) {
                const float xc = (q==0) ? x.x : (q==1) ? x.y : (q==2) ? x.z : x.w;
                nmin = fminf(nmin, xc);
                smin = fminf(smin, (xc > lo2 && xc < hi2) ? xc : BIGV);
            }
        }
        #pragma unroll
        for (int off = 1; off < 64; off <<= 1) {
            nmin = fminf(nmin, __shfl_xor(nmin, off));
            smin = fminf(smin, __shfl_xor(smin, off));
        }
        if (lane == 0) {
            const bool has_neg  = nmin < 0.5f*BIGV;
            const bool has_semi = smin < 0.5f*BIGV;
            const float dan2 = has_semi ? smin : nmin;
            const float dap  = has_pos ? sqrtf(dap2) : 0.f;
            float t = dap - sqrtf(dan2) + MARGINF;
            t = t > 0.f ? t : 0.f;
            const bool valid = has_pos && has_neg;
            accT += valid ? t : 0.f;
            accV += valid ? 1.f : 0.f;
        }
    }
    if (lane == 0) { sT[w] = accT; sV[w] = accV; }
    __syncthreads();
    if (tid == 0) {
        float st = 0.f, sv = 0.f;
        #pragma unroll
        for (int q = 0; q < 8; ++q) { st += sT[q]; sv += sV[q]; }
        double* dsum = (double*)flags;              // 8B-aligned (host-checked)
        unsigned* dcnt = (unsigned*)(flags + 2);
        atomicAdd(dsum, (double)st + (double)sv * 65536.0);
        asm volatile("s_waitcnt vmcnt(0)" ::: "memory");
        const unsigned oc = atomicAdd(dcnt, 1u);
        if (oc == 15u) {                            // last of 16, order-independent
            const double fin = atomicAdd(dsum, 0.0);
            const double svt = floor(fin / 65536.0);
            const double stt = fin - svt * 65536.0;
            out[0] = (float)(stt / (svt > 1.0 ? svt : 1.0));
        }
    }
}

extern "C" void kernel_launch(void* const* d_in, const int* in_sizes, int n_in,
                              void* d_out, int out_size, void* d_ws, size_t ws_size,
                              hipStream_t stream) {
    const float* emb = (const float*)d_in[0];   // [1024,256] f32
    const float* gps = (const float*)d_in[1];   // [1024,2]  f32
    float* ws = (float*)d_ws;

    float* sEnc  = ws;                    // 1024*1024 f32 = 4 MB
    float* pP    = ws + 1048576;          // 1024*16
    float* flags = pP + 16384;            // double cell (8B-aligned) + counter

    gram_mfma<<<256, 256, 0, stream>>>(emb, gps, sEnc, pP, flags);
    rows_final<<<16, 512, 0, stream>>>(sEnc, pP, flags, (float*)d_out);
}